// Round 6
// baseline (48.406 us; speedup 1.0000x reference)
//
#include <hip/hip_runtime.h>
#include <math.h>

// Sliding-window (n=64) temperature-softmax attention, fp32, N=4194304.
// ROUND 6 = COUNTER-VISIBILITY DIAGNOSTIC: exact round-4 kernel body repeated
// REP=4x inside one dispatch (asm-laundered pointers defeat LICM/CSE; output
// rewritten idempotently) so our dispatch exceeds the 40us poison fills and
// appears in the rocprof top-5 with its own FETCH/WRITE/VALUBusy/VGPR row.

#define SEG 16
#define BLK 256
#define HALO 4
#define ROWS (BLK + HALO)      // 260
#define RSTRIDE 20             // floats per LDS row (16 data + 4 pad)
#define REP 4

__device__ __forceinline__ float fexp2(float x) { return __builtin_amdgcn_exp2f(x); }

__global__ __launch_bounds__(256, 4) void soft_attn_kernel(
    const float* __restrict__ x_in, const float* __restrict__ w_tau,
    float* __restrict__ out_in)
{
    __shared__ float lds[ROWS * RSTRIDE];   // 20800 B

    const int tid = threadIdx.x;
    const int S0  = blockIdx.x * BLK;
    const int s   = S0 + tid;

    unsigned long long xa = (unsigned long long)(uintptr_t)x_in;
    unsigned long long oa = (unsigned long long)(uintptr_t)out_in;

#pragma unroll 1
    for (int rep = 0; rep < REP; ++rep) {
        // Launder pointers: compiler cannot prove iterations identical.
        asm volatile("" : "+s"(xa), "+s"(oa) :: "memory");
        const float* __restrict__ x = (const float*)(uintptr_t)xa;
        float* __restrict__ out = (float*)(uintptr_t)oa;

        const float tau = log1pf(expf(w_tau[0])) + 1e-5f;
        const float C = 1.4426950408889634f / tau;

        // ---- Stage [S0-4, S0+256) segments into LDS, coalesced ----
        {
            const int base4 = (S0 - HALO) * (SEG / 4);
#pragma unroll
            for (int it = 0; it < 5; ++it) {
                const int i = tid + it * BLK;
                if (i < ROWS * 4) {
                    const int g4 = base4 + i;
                    if (g4 >= 0) {
                        const float4 t = reinterpret_cast<const float4*>(x)[g4];
                        const int r = i >> 2, c = i & 3;
                        *reinterpret_cast<float4*>(&lds[r * RSTRIDE + c * 4]) = t;
                    }
                }
            }
        }
        __syncthreads();

#define STEP(val, M, R0, R1)                                   \
        {                                                      \
            const float _v = (val);                            \
            const float _e = fexp2(-fabsf((M) - _v) * C);      \
            const float _ea = (_v >= (M)) ? 1.f : _e;          \
            const float _eb = (_v >= (M)) ? _e : 1.f;          \
            (R0) = (R0) * _eb + _ea;                           \
            (R1) = (R1) * _eb + _v * _ea;                      \
            (M) = fmaxf((M), _v);                              \
        }

        float Sm[SEG], Sa[SEG], Sb[SEG];
        float m = -INFINITY, r0 = 0.f, r1 = 0.f;

        const bool fast = (blockIdx.x != 0) || (tid >= HALO);
        if (fast) {
            const float* row0 = &lds[tid * RSTRIDE];
            float v0[SEG];
#pragma unroll
            for (int c = 0; c < 4; ++c) {
                const float4 t = *reinterpret_cast<const float4*>(row0 + 4 * c);
                v0[4*c] = t.x; v0[4*c+1] = t.y; v0[4*c+2] = t.z; v0[4*c+3] = t.w;
            }
            float sm = -INFINITY, sa = 0.f, sb = 0.f;
            Sm[SEG-1] = -INFINITY; Sa[SEG-1] = 0.f; Sb[SEG-1] = 0.f;
#pragma unroll
            for (int q = SEG - 1; q >= 1; --q) {
                STEP(v0[q], sm, sa, sb);
                Sm[q-1] = sm; Sa[q-1] = sa; Sb[q-1] = sb;
            }
#pragma unroll
            for (int r = 1; r <= 3; ++r) {
                const float* row = &lds[(tid + r) * RSTRIDE];
#pragma unroll
                for (int c = 0; c < 4; ++c) {
                    const float4 t = *reinterpret_cast<const float4*>(row + 4 * c);
                    STEP(t.x, m, r0, r1); STEP(t.y, m, r0, r1);
                    STEP(t.z, m, r0, r1); STEP(t.w, m, r0, r1);
                }
            }
        } else {
#pragma unroll
            for (int q = 0; q < SEG; ++q) { Sm[q] = -INFINITY; Sa[q] = 0.f; Sb[q] = 0.f; }
            for (int t = s - 3; t < s; ++t) {
                if (t >= 0) {
                    const float* p = x + (size_t)t * SEG;
                    for (int q = 0; q < SEG; ++q) STEP(p[q], m, r0, r1);
                }
            }
        }

        const float* rowe = &lds[(tid + HALO) * RSTRIDE];
        float4* o4 = reinterpret_cast<float4*>(out + (size_t)s * SEG);
#pragma unroll
        for (int c = 0; c < 4; ++c) {
            const float4 t = *reinterpret_cast<const float4*>(rowe + 4 * c);
            float4 ob;
#pragma unroll
            for (int j = 0; j < 4; ++j) {
                const int p = 4 * c + j;
                const float val = (j == 0) ? t.x : (j == 1) ? t.y : (j == 2) ? t.z : t.w;
                STEP(val, m, r0, r1);
                const float smv = Sm[p];
                const float ec  = fexp2(-fabsf(m - smv) * C);
                const float e1  = (m >= smv) ? 1.f : ec;
                const float e2  = (m >= smv) ? ec : 1.f;
                const float t0  = r0 * e1 + Sa[p] * e2;
                const float t1  = r1 * e1 + Sb[p] * e2;
                const float res = t1 * __builtin_amdgcn_rcpf(t0);
                if      (j == 0) ob.x = res;
                else if (j == 1) ob.y = res;
                else if (j == 2) ob.z = res;
                else             ob.w = res;
            }
            o4[c] = ob;
        }
#undef STEP
        __syncthreads();   // LDS WAR guard before next iteration's staging
    }
}

extern "C" void kernel_launch(void* const* d_in, const int* in_sizes, int n_in,
                              void* d_out, int out_size, void* d_ws, size_t ws_size,
                              hipStream_t stream) {
    const float* x = (const float*)d_in[0];
    const float* w = (const float*)d_in[1];
    float* outp = (float*)d_out;
    const int N = in_sizes[0];                 // 4194304
    const int nseg = N / SEG;                  // 262144
    const int blocks = nseg / BLK;             // 1024
    soft_attn_kernel<<<blocks, BLK, 0, stream>>>(x, w, outp);
}

// Round 7
// 17.444 us; speedup vs baseline: 2.7749x; 2.7749x over previous
//
#include <hip/hip_runtime.h>
#include <math.h>

// Sliding-window (n=64) temperature-softmax attention, fp32, N=4194304.
// Round 7: L=32 two-sided scan (exp2/output 6 -> 3.97; VALU/output 55 -> ~41).
// R6 counters showed v_exp_f32 (~33 cyc/wave) is ~40% of exec -> attack exp count.
// Finite PAD sentinel (-1e30) staged into LDS halo removes all edge divergence:
// pad weight = exp2(-|m-pad|*C) == 0 exactly; no inf-inf NaN.

#define SEG 32
#define BLK 256
#define ROWS (BLK + 2)        // 258 segments: [S0-2, S0+255]
#define RSTRIDE 36            // 32 data + 4 pad floats -> conflict-min ds_read_b128
#define PADV -1.0e30f

__device__ __forceinline__ float fexp2(float x) { return __builtin_amdgcn_exp2f(x); }

__global__ __launch_bounds__(256, 2) void soft_attn_kernel(
    const float* __restrict__ x, const float* __restrict__ w_tau,
    float* __restrict__ out)
{
    __shared__ float lds[ROWS * RSTRIDE];   // 37152 B

    const int tid = threadIdx.x;
    const int S0  = blockIdx.x * BLK;       // first owned segment of this block
    const int s   = S0 + tid;               // this thread's segment

    const float tau = log1pf(expf(w_tau[0])) + 1e-5f;
    const float C = 1.4426950408889634f / tau;   // log2(e)/tau

    // ---- Stage segments [S0-2, S0+255] into LDS rows 0..257, coalesced.
    // Negative global indices (block 0 halo) get the PAD sentinel.
    {
        const int base4 = (S0 - 2) * (SEG / 4);
#pragma unroll
        for (int it = 0; it < 9; ++it) {
            const int i = tid + it * BLK;            // float4 index in region
            if (i < ROWS * (SEG / 4)) {              // < 2064
                const int g4 = base4 + i;
                float4 t;
                if (g4 >= 0) t = reinterpret_cast<const float4*>(x)[g4];
                else         t = make_float4(PADV, PADV, PADV, PADV);
                const int r = i >> 3, c = i & 7;
                *reinterpret_cast<float4*>(&lds[r * RSTRIDE + c * 4]) = t;
            }
        }
    }
    __syncthreads();

    // online-softmax monoid append; one exp2 per element
#define STEP(val, M, R0, R1)                                   \
    {                                                          \
        const float _v = (val);                                \
        const float _e = fexp2(-fabsf((M) - _v) * C);          \
        const float _ea = (_v >= (M)) ? 1.f : _e;              \
        const float _eb = (_v >= (M)) ? _e : 1.f;              \
        (R0) = (R0) * _eb + _ea;                               \
        (R1) = (R1) * _eb + _v * _ea;                          \
        (M) = fmaxf((M), _v);                                  \
    }

    // ---- Suffix scan over seg s-2 (LDS row tid), backwards.
    // Slot p holds scan of elements [p+1 .. 31]; slot 31 = empty.
    float Sm[SEG], Sa[SEG], Sb[SEG];
    {
        const float* row0 = &lds[tid * RSTRIDE];
        float sm = PADV, sa = 0.f, sb = 0.f;
        Sm[31] = PADV; Sa[31] = 0.f; Sb[31] = 0.f;
#pragma unroll
        for (int c = 7; c >= 0; --c) {
            const float4 t = *reinterpret_cast<const float4*>(row0 + 4 * c);
            STEP(t.w, sm, sa, sb); Sm[4*c+2] = sm; Sa[4*c+2] = sa; Sb[4*c+2] = sb;
            STEP(t.z, sm, sa, sb); Sm[4*c+1] = sm; Sa[4*c+1] = sa; Sb[4*c+1] = sb;
            STEP(t.y, sm, sa, sb); Sm[4*c+0] = sm; Sa[4*c+0] = sa; Sb[4*c+0] = sb;
            if (c > 0) { STEP(t.x, sm, sa, sb); Sm[4*c-1] = sm; Sa[4*c-1] = sa; Sb[4*c-1] = sb; }
        }
    }

    // ---- Prefix scan over seg s-1 (LDS row tid+1), full 32 elements.
    float m = PADV, r0 = 0.f, r1 = 0.f;
    {
        const float* row1 = &lds[(tid + 1) * RSTRIDE];
#pragma unroll
        for (int c = 0; c < 8; ++c) {
            const float4 t = *reinterpret_cast<const float4*>(row1 + 4 * c);
            STEP(t.x, m, r0, r1); STEP(t.y, m, r0, r1);
            STEP(t.z, m, r0, r1); STEP(t.w, m, r0, r1);
        }
    }

    // ---- Emission over seg s (LDS row tid+2): continue prefix, combine with suffix.
    const float* row2 = &lds[(tid + 2) * RSTRIDE];
    float4* o4 = reinterpret_cast<float4*>(out + (size_t)s * SEG);
#pragma unroll
    for (int c = 0; c < 8; ++c) {
        const float4 t = *reinterpret_cast<const float4*>(row2 + 4 * c);
        float4 ob;
#pragma unroll
        for (int j = 0; j < 4; ++j) {
            const int p = 4 * c + j;
            const float val = (j == 0) ? t.x : (j == 1) ? t.y : (j == 2) ? t.z : t.w;
            STEP(val, m, r0, r1);
            const float smv = Sm[p];
            const float ec  = fexp2(-fabsf(m - smv) * C);
            const float e1  = (m >= smv) ? 1.f : ec;
            const float e2  = (m >= smv) ? ec : 1.f;
            const float t0  = r0 * e1 + Sa[p] * e2;
            const float t1  = r1 * e1 + Sb[p] * e2;
            const float res = t1 * __builtin_amdgcn_rcpf(t0);  // t0 in [1,64]
            if      (j == 0) ob.x = res;
            else if (j == 1) ob.y = res;
            else if (j == 2) ob.z = res;
            else             ob.w = res;
        }
        o4[c] = ob;
    }
#undef STEP
}

extern "C" void kernel_launch(void* const* d_in, const int* in_sizes, int n_in,
                              void* d_out, int out_size, void* d_ws, size_t ws_size,
                              hipStream_t stream) {
    const float* x = (const float*)d_in[0];
    const float* w = (const float*)d_in[1];
    float* outp = (float*)d_out;
    const int N = in_sizes[0];                 // 4194304
    const int nseg = N / SEG;                  // 131072
    const int blocks = nseg / BLK;             // 512
    soft_attn_kernel<<<blocks, BLK, 0, stream>>>(x, w, outp);
}

// Round 8
// 17.417 us; speedup vs baseline: 2.7792x; 1.0015x over previous
//
#include <hip/hip_runtime.h>
#include <math.h>

// Sliding-window (n=64) temperature-softmax attention, fp32, N=4194304.
// Round 8: same L=32 two-sided scan as R7, but suffix triples (96 floats) are
// forced into VGPRs via ext_vector_type(32) with static-only indexing.
// R6's VGPR_Count=48 proved the plain float[] arrays were allocated in
// SCRATCH (private mem) -> ~50-100MB hidden store+load traffic, the invariant
// ~12us cost across R1/R2/R4/R7. Cap 256 VGPR via __launch_bounds__(256,2).

#define SEG 32
#define BLK 256
#define ROWS (BLK + 2)        // 258 segments: [S0-2, S0+255]
#define RSTRIDE 36            // 32 data + 4 pad floats
#define PADV -1.0e30f

typedef float f32x32 __attribute__((ext_vector_type(32)));

__device__ __forceinline__ float fexp2(float x) { return __builtin_amdgcn_exp2f(x); }

__global__ __launch_bounds__(256, 2) void soft_attn_kernel(
    const float* __restrict__ x, const float* __restrict__ w_tau,
    float* __restrict__ out)
{
    __shared__ float lds[ROWS * RSTRIDE];   // 37152 B

    const int tid = threadIdx.x;
    const int S0  = blockIdx.x * BLK;       // first owned segment of this block
    const int s   = S0 + tid;               // this thread's segment

    const float tau = log1pf(expf(w_tau[0])) + 1e-5f;
    const float C = 1.4426950408889634f / tau;   // log2(e)/tau

    // ---- Stage segments [S0-2, S0+255] into LDS rows 0..257, coalesced.
    {
        const int base4 = (S0 - 2) * (SEG / 4);
#pragma unroll
        for (int it = 0; it < 9; ++it) {
            const int i = tid + it * BLK;            // float4 index in region
            if (i < ROWS * (SEG / 4)) {              // < 2064
                const int g4 = base4 + i;
                float4 t;
                if (g4 >= 0) t = reinterpret_cast<const float4*>(x)[g4];
                else         t = make_float4(PADV, PADV, PADV, PADV);
                const int r = i >> 3, c = i & 7;
                *reinterpret_cast<float4*>(&lds[r * RSTRIDE + c * 4]) = t;
            }
        }
    }
    __syncthreads();

    // online-softmax monoid append; one exp2 per element
#define STEP(val, M, R0, R1)                                   \
    {                                                          \
        const float _v = (val);                                \
        const float _e = fexp2(-fabsf((M) - _v) * C);          \
        const float _ea = (_v >= (M)) ? 1.f : _e;              \
        const float _eb = (_v >= (M)) ? _e : 1.f;              \
        (R0) = (R0) * _eb + _ea;                               \
        (R1) = (R1) * _eb + _v * _ea;                          \
        (M) = fmaxf((M), _v);                                  \
    }

    // ---- Suffix scan over seg s-2 (LDS row tid), backwards.
    // Slot p holds scan of elements [p+1 .. 31]; slot 31 = empty.
    // ext_vector + static indices only => guaranteed VGPR residency.
    f32x32 Sm, Sa, Sb;
    {
        const float* row0 = &lds[tid * RSTRIDE];
        float sm = PADV, sa = 0.f, sb = 0.f;
        Sm[31] = PADV; Sa[31] = 0.f; Sb[31] = 0.f;
#pragma unroll
        for (int c = 7; c >= 0; --c) {
            const float4 t = *reinterpret_cast<const float4*>(row0 + 4 * c);
            STEP(t.w, sm, sa, sb); Sm[4*c+2] = sm; Sa[4*c+2] = sa; Sb[4*c+2] = sb;
            STEP(t.z, sm, sa, sb); Sm[4*c+1] = sm; Sa[4*c+1] = sa; Sb[4*c+1] = sb;
            STEP(t.y, sm, sa, sb); Sm[4*c+0] = sm; Sa[4*c+0] = sa; Sb[4*c+0] = sb;
            if (c > 0) { STEP(t.x, sm, sa, sb); Sm[4*c-1] = sm; Sa[4*c-1] = sa; Sb[4*c-1] = sb; }
        }
    }

    // ---- Prefix scan over seg s-1 (LDS row tid+1), full 32 elements.
    float m = PADV, r0 = 0.f, r1 = 0.f;
    {
        const float* row1 = &lds[(tid + 1) * RSTRIDE];
#pragma unroll
        for (int c = 0; c < 8; ++c) {
            const float4 t = *reinterpret_cast<const float4*>(row1 + 4 * c);
            STEP(t.x, m, r0, r1); STEP(t.y, m, r0, r1);
            STEP(t.z, m, r0, r1); STEP(t.w, m, r0, r1);
        }
    }

    // ---- Emission over seg s (LDS row tid+2): continue prefix, combine with suffix.
    const float* row2 = &lds[(tid + 2) * RSTRIDE];
    float4* o4 = reinterpret_cast<float4*>(out + (size_t)s * SEG);
#pragma unroll
    for (int c = 0; c < 8; ++c) {
        const float4 t = *reinterpret_cast<const float4*>(row2 + 4 * c);
        float4 ob;
#pragma unroll
        for (int j = 0; j < 4; ++j) {
            const int p = 4 * c + j;
            const float val = (j == 0) ? t.x : (j == 1) ? t.y : (j == 2) ? t.z : t.w;
            STEP(val, m, r0, r1);
            const float smv = Sm[p];
            const float ec  = fexp2(-fabsf(m - smv) * C);
            const float e1  = (m >= smv) ? 1.f : ec;
            const float e2  = (m >= smv) ? ec : 1.f;
            const float t0  = r0 * e1 + Sa[p] * e2;
            const float t1  = r1 * e1 + Sb[p] * e2;
            const float res = t1 * __builtin_amdgcn_rcpf(t0);  // t0 in [1,64]
            if      (j == 0) ob.x = res;
            else if (j == 1) ob.y = res;
            else if (j == 2) ob.z = res;
            else             ob.w = res;
        }
        o4[c] = ob;
    }
#undef STEP
}

extern "C" void kernel_launch(void* const* d_in, const int* in_sizes, int n_in,
                              void* d_out, int out_size, void* d_ws, size_t ws_size,
                              hipStream_t stream) {
    const float* x = (const float*)d_in[0];
    const float* w = (const float*)d_in[1];
    float* outp = (float*)d_out;
    const int N = in_sizes[0];                 // 4194304
    const int nseg = N / SEG;                  // 131072
    const int blocks = nseg / BLK;             // 512
    soft_attn_kernel<<<blocks, BLK, 0, stream>>>(x, w, outp);
}

// Round 9
// 17.246 us; speedup vs baseline: 2.8068x; 1.0099x over previous
//
#include <hip/hip_runtime.h>
#include <math.h>

// Sliding-window (n=64) temperature-softmax attention, fp32, N=4194304.
// Round 9: R8 kernel with the REGISTER CAP REMOVED. Every prior round carried
// __launch_bounds__(256, minwaves>=2) -> VGPR cap 64..128 < the ~150 live
// floats of scan state -> forced scratch spills (R6: VGPR_Count=48 with 48+
// floats of state; ~97MB/rep spill traffic = the invariant ~13us exec cost).
// One-arg __launch_bounds__(256) lifts the cap to 256 VGPRs: state fits, no
// spills, 2-3 waves/SIMD.

#define SEG 32
#define BLK 256
#define ROWS (BLK + 2)        // 258 segments: [S0-2, S0+255]
#define RSTRIDE 36            // 32 data + 4 pad floats
#define PADV -1.0e30f

typedef float f32x32 __attribute__((ext_vector_type(32)));

__device__ __forceinline__ float fexp2(float x) { return __builtin_amdgcn_exp2f(x); }

__global__ __launch_bounds__(256) void soft_attn_kernel(
    const float* __restrict__ x, const float* __restrict__ w_tau,
    float* __restrict__ out)
{
    __shared__ float lds[ROWS * RSTRIDE];   // 37152 B

    const int tid = threadIdx.x;
    const int S0  = blockIdx.x * BLK;       // first owned segment of this block
    const int s   = S0 + tid;               // this thread's segment

    const float tau = log1pf(expf(w_tau[0])) + 1e-5f;
    const float C = 1.4426950408889634f / tau;   // log2(e)/tau

    // ---- Stage segments [S0-2, S0+255] into LDS rows 0..257, coalesced.
    {
        const int base4 = (S0 - 2) * (SEG / 4);
#pragma unroll
        for (int it = 0; it < 9; ++it) {
            const int i = tid + it * BLK;            // float4 index in region
            if (i < ROWS * (SEG / 4)) {              // < 2064
                const int g4 = base4 + i;
                float4 t;
                if (g4 >= 0) t = reinterpret_cast<const float4*>(x)[g4];
                else         t = make_float4(PADV, PADV, PADV, PADV);
                const int r = i >> 3, c = i & 7;
                *reinterpret_cast<float4*>(&lds[r * RSTRIDE + c * 4]) = t;
            }
        }
    }
    __syncthreads();

    // online-softmax monoid append; one exp2 per element
#define STEP(val, M, R0, R1)                                   \
    {                                                          \
        const float _v = (val);                                \
        const float _e = fexp2(-fabsf((M) - _v) * C);          \
        const float _ea = (_v >= (M)) ? 1.f : _e;              \
        const float _eb = (_v >= (M)) ? _e : 1.f;              \
        (R0) = (R0) * _eb + _ea;                               \
        (R1) = (R1) * _eb + _v * _ea;                          \
        (M) = fmaxf((M), _v);                                  \
    }

    // ---- Suffix scan over seg s-2 (LDS row tid), backwards.
    // Slot p holds scan of elements [p+1 .. 31]; slot 31 = empty.
    f32x32 Sm, Sa, Sb;
    {
        const float* row0 = &lds[tid * RSTRIDE];
        float sm = PADV, sa = 0.f, sb = 0.f;
        Sm[31] = PADV; Sa[31] = 0.f; Sb[31] = 0.f;
#pragma unroll
        for (int c = 7; c >= 0; --c) {
            const float4 t = *reinterpret_cast<const float4*>(row0 + 4 * c);
            STEP(t.w, sm, sa, sb); Sm[4*c+2] = sm; Sa[4*c+2] = sa; Sb[4*c+2] = sb;
            STEP(t.z, sm, sa, sb); Sm[4*c+1] = sm; Sa[4*c+1] = sa; Sb[4*c+1] = sb;
            STEP(t.y, sm, sa, sb); Sm[4*c+0] = sm; Sa[4*c+0] = sa; Sb[4*c+0] = sb;
            if (c > 0) { STEP(t.x, sm, sa, sb); Sm[4*c-1] = sm; Sa[4*c-1] = sa; Sb[4*c-1] = sb; }
        }
    }

    // ---- Prefix scan over seg s-1 (LDS row tid+1), full 32 elements.
    float m = PADV, r0 = 0.f, r1 = 0.f;
    {
        const float* row1 = &lds[(tid + 1) * RSTRIDE];
#pragma unroll
        for (int c = 0; c < 8; ++c) {
            const float4 t = *reinterpret_cast<const float4*>(row1 + 4 * c);
            STEP(t.x, m, r0, r1); STEP(t.y, m, r0, r1);
            STEP(t.z, m, r0, r1); STEP(t.w, m, r0, r1);
        }
    }

    // ---- Emission over seg s (LDS row tid+2): continue prefix, combine with suffix.
    const float* row2 = &lds[(tid + 2) * RSTRIDE];
    float4* o4 = reinterpret_cast<float4*>(out + (size_t)s * SEG);
#pragma unroll
    for (int c = 0; c < 8; ++c) {
        const float4 t = *reinterpret_cast<const float4*>(row2 + 4 * c);
        float4 ob;
#pragma unroll
        for (int j = 0; j < 4; ++j) {
            const int p = 4 * c + j;
            const float val = (j == 0) ? t.x : (j == 1) ? t.y : (j == 2) ? t.z : t.w;
            STEP(val, m, r0, r1);
            const float smv = Sm[p];
            const float ec  = fexp2(-fabsf(m - smv) * C);
            const float e1  = (m >= smv) ? 1.f : ec;
            const float e2  = (m >= smv) ? ec : 1.f;
            const float t0  = r0 * e1 + Sa[p] * e2;
            const float t1  = r1 * e1 + Sb[p] * e2;
            const float res = t1 * __builtin_amdgcn_rcpf(t0);  // t0 in [1,64]
            if      (j == 0) ob.x = res;
            else if (j == 1) ob.y = res;
            else if (j == 2) ob.z = res;
            else             ob.w = res;
        }
        o4[c] = ob;
    }
#undef STEP
}

extern "C" void kernel_launch(void* const* d_in, const int* in_sizes, int n_in,
                              void* d_out, int out_size, void* d_ws, size_t ws_size,
                              hipStream_t stream) {
    const float* x = (const float*)d_in[0];
    const float* w = (const float*)d_in[1];
    float* outp = (float*)d_out;
    const int N = in_sizes[0];                 // 4194304
    const int nseg = N / SEG;                  // 131072
    const int blocks = nseg / BLK;             // 512
    soft_attn_kernel<<<blocks, BLK, 0, stream>>>(x, w, outp);
}